// Round 18
// baseline (195.973 us; speedup 1.0000x reference)
//
#include <hip/hip_runtime.h>
#include <float.h>

typedef _Float16 half8 __attribute__((ext_vector_type(8)));
typedef float    f32x4 __attribute__((ext_vector_type(4)));
typedef unsigned long long u64;

#define N_ROWS   65536
#define DIM      256
#define KCODES   1024
#define VQ_BETA  0.25
#define MARGIN   1.5f   // hard bound: need > 2*eps = 0.82 (eps <= 2^-10*||x||*||e|| = 0.41)
#define HCAP     640

// ---------------------------------------------------------------------------
// Order-preserving float->uint key (monotone, handles negatives)
__device__ __forceinline__ unsigned fkey(float f) {
    const unsigned u = __float_as_uint(f);
    return u ^ (0x80000000u | (unsigned)((int)u >> 31));
}

// ---------------------------------------------------------------------------
// Kernel 0: transpose E [256][1024] -> Et [1024][256] fp32 (rescore + gather)
__global__ void transpose_e(const float* __restrict__ E, float* __restrict__ Et) {
    __shared__ float t[32][33];
    const int kt = blockIdx.x * 32;
    const int dt = blockIdx.y * 32;
    const int lx = threadIdx.x & 31;
    const int ly = threadIdx.x >> 5;
#pragma unroll
    for (int i = 0; i < 4; ++i) {
        int d = dt + ly + i * 8;
        t[ly + i * 8][lx] = E[(size_t)d * KCODES + kt + lx];
    }
    __syncthreads();
#pragma unroll
    for (int i = 0; i < 4; ++i) {
        int k = kt + ly + i * 8;
        Et[(size_t)k * DIM + dt + lx] = t[lx][ly + i * 8];
    }
}

// ---------------------------------------------------------------------------
// Kernel 1: e_norm[k] = sum_d E[d][k]^2 (fp32, sequential d order)
__global__ void enorm_kernel(const float* __restrict__ E, float* __restrict__ enorm) {
    const int k = blockIdx.x * 256 + threadIdx.x;
    float s = 0.f;
#pragma unroll 4
    for (int d = 0; d < DIM; ++d) {
        float v = E[(size_t)d * KCODES + k];
        s = fmaf(v, v, s);
    }
    enorm[k] = s;
}

// ---------------------------------------------------------------------------
// Kernel 2: pack Et into fp16 B fragments, wave-coalesced layout (round-8
// mapping: code = chunk*256 + w*64 + nt*16 + llo, w in 0..3, nt in 0..3).
__global__ void efrag_kernel(const float* __restrict__ Et, _Float16* __restrict__ Efb) {
    const int fid = blockIdx.x * 256 + threadIdx.x;   // 0..32767
    const int lhi   = fid & 3;
    const int llo   = (fid >> 2) & 15;
    const int nt    = (fid >> 6) & 3;
    const int w     = (fid >> 8) & 3;
    const int slice = fid >> 10;                      // 0..31
    const int chunk = slice >> 3, ks = slice & 7;
    const int code  = chunk * 256 + w * 64 + nt * 16 + llo;
    const float* src = Et + (size_t)code * DIM + ks * 32 + lhi * 8;
    half8 h;
#pragma unroll
    for (int j = 0; j < 8; ++j) h[j] = (_Float16)src[j];
    *reinterpret_cast<half8*>(Efb + (size_t)fid * 8) = h;
}

// ---------------------------------------------------------------------------
__device__ __forceinline__ void load_bf4(const _Float16* __restrict__ eb,
                                         half8 (&bf)[4]) {
    bf[0] = *reinterpret_cast<const half8*>(eb);
    bf[1] = *reinterpret_cast<const half8*>(eb + 512);
    bf[2] = *reinterpret_cast<const half8*>(eb + 1024);
    bf[3] = *reinterpret_cast<const half8*>(eb + 1536);
}
__device__ __forceinline__ void load_af(const char* AhB, int ks, int llo, int lhi,
                                        int aswz, half8 (&af)[4]) {
#pragma unroll
    for (int mt = 0; mt < 4; ++mt) {
        const int addr = ((mt * 16 + llo) * 512 + (ks * 4 + lhi) * 16) ^ aswz;
        af[mt] = *reinterpret_cast<const half8*>(AhB + addr);
    }
}
__device__ __forceinline__ void mfma16(const half8 (&af)[4], const half8 (&bf)[4],
                                       f32x4 (&acc)[4][4]) {
#pragma unroll
    for (int mt = 0; mt < 4; ++mt)
#pragma unroll
        for (int nt = 0; nt < 4; ++nt)
            acc[mt][nt] = __builtin_amdgcn_mfma_f32_16x16x32_f16(
                af[mt], bf[nt], acc[mt][nt], 0, 0, 0);
}
// Round-8 K-loop geometry: 64 rows x 64 codes x K=256 per wave, 16 MFMA per
// 4 ds_read (2x the compute density per LDS access of the 512-thread shape
// that was pinned at ~141us). B direct from global (L2-hot), double-buffered;
// A from swizzled LDS; NO barriers. Proven 128-VGPR spill-free (round 8).
__device__ __forceinline__ void mfma_chunk(
        const _Float16* __restrict__ ebase, const char* AhB,
        int llo, int lhi, int aswz, f32x4 (&acc)[4][4]) {
    half8 bfa[4], bfb[4], af[4];
    load_bf4(ebase, bfa);
#pragma unroll
    for (int ks2 = 0; ks2 < 4; ++ks2) {
        const int ksA = ks2 * 2, ksB = ks2 * 2 + 1;
        load_bf4(ebase + (size_t)ksB * 8192, bfb);
        load_af(AhB, ksA, llo, lhi, aswz, af);
        mfma16(af, bfa, acc);
        if (ksB < 7) load_bf4(ebase + (size_t)(ksB + 1) * 8192, bfa);
        load_af(AhB, ksB, llo, lhi, aswz, af);
        mfma16(af, bfb, acc);
    }
}

// ---------------------------------------------------------------------------
// Kernel 3: single-pass pruned argmin + fused epilogue, ROUND-8 GEOMETRY.
// 256 thr = 4 waves, 64 rows/block, 64 codes/wave/chunk (acc[4][4]).
// Chunk 0: MFMA -> block row-min (the ONLY 2 barriers) -> frozen cutoff.
// Chunks 1-3: barrier-free {MFMA -> ds -> LDS-broadcast filter}.
// Sound: min_chunk0 >= true min; winner has ds~ <= d_min + eps
// <= min_chunk0 + 2*eps < cut (MARGIN 1.5 > 2*eps = 0.82); superset to
// exact rescore, winner always self-qualifies.
// Rescore winner via ONE packed 64-bit LDS atomicMin per row:
//   key = (fkey(dd)<<10)|code  == np first-min tie-break.
__global__ __launch_bounds__(256, 2) void vq_mfma(
        const float* __restrict__ X, const _Float16* __restrict__ Efb,
        const float* __restrict__ enorm, const float* __restrict__ Et,
        float* __restrict__ outidx, float* __restrict__ outq,
        float* __restrict__ partials)
{
    __shared__ _Float16 Ah[64 * 256];     // 32 KB, swizzled
    __shared__ float    bminw[4][64];     // 1 KB
    __shared__ float    cutoff_s[64];
    __shared__ u64      minpk[64];        // packed (fkey(dd)<<10)|code
    __shared__ int      rowbad[64];
    __shared__ int      hits[HCAP];       // 2.5 KB
    __shared__ float    xs[DIM];          // 1 KB (fallback row cache)
    __shared__ float    wlsum[4];
    __shared__ unsigned hitcnt;

    const int tid = threadIdx.x;
    const int rowbase = blockIdx.x * 64;

    if (tid == 0) hitcnt = 0;
    if (tid < 64) {
        minpk[tid] = 0xFFFFFFFFFFFFFFFFULL;
        rowbad[tid] = 0;
    }

    // ---- stage A tile: fp32 -> fp16 swizzled LDS (4 threads/row) ----
    {
        const int row = tid >> 2;
#pragma unroll
        for (int i = 0; i < 8; ++i) {
            const int g = (tid & 3) + 4 * i;        // 16B-chunk index 0..31
            const float* src = X + (size_t)(rowbase + row) * DIM + g * 8;
            float4 a = *reinterpret_cast<const float4*>(src);
            float4 b = *reinterpret_cast<const float4*>(src + 4);
            half8 h;
            h[0] = (_Float16)a.x; h[1] = (_Float16)a.y;
            h[2] = (_Float16)a.z; h[3] = (_Float16)a.w;
            h[4] = (_Float16)b.x; h[5] = (_Float16)b.y;
            h[6] = (_Float16)b.z; h[7] = (_Float16)b.w;
            const int addr = (row * 512 + g * 16) ^ ((row & 7) << 4);
            *reinterpret_cast<half8*>(reinterpret_cast<char*>(Ah) + addr) = h;
        }
    }
    __syncthreads();

    const int w    = tid >> 6;            // 0..3
    const int lane = tid & 63;
    const int lhi  = lane >> 4, llo = lane & 15;
    const int aswz = (llo & 7) << 4;
    const int lane_off8 = (llo * 4 + lhi) * 8;
    const char* AhB = reinterpret_cast<const char*>(Ah);

    // ============== CHUNK 0: MFMA + the ONLY block-wide reduce ==============
    {
        f32x4 acc[4][4];
#pragma unroll
        for (int mt = 0; mt < 4; ++mt)
#pragma unroll
            for (int nt = 0; nt < 4; ++nt) acc[mt][nt] = (f32x4){0.f, 0.f, 0.f, 0.f};

        float e2v[4];
#pragma unroll
        for (int nt = 0; nt < 4; ++nt)
            e2v[nt] = enorm[w * 64 + nt * 16 + llo];

        const _Float16* ebase = Efb + w * 2048 + lane_off8;
        mfma_chunk(ebase, AhB, llo, lhi, aswz, acc);

        // ds in place (acc := e2 - 2*S~), per-slot min over nt
        float mloc[16];
#pragma unroll
        for (int mt = 0; mt < 4; ++mt)
#pragma unroll
            for (int q = 0; q < 4; ++q) {
                float m = FLT_MAX;
#pragma unroll
                for (int nt = 0; nt < 4; ++nt) {
                    const float ds = fmaf(-2.0f, acc[mt][nt][q], e2v[nt]);
                    acc[mt][nt][q] = ds;
                    m = fminf(m, ds);
                }
                mloc[mt * 4 + q] = m;
            }
        // min across the 16 llo lanes (same rows)
#pragma unroll
        for (int m = 1; m < 16; m <<= 1)
#pragma unroll
            for (int sl = 0; sl < 16; ++sl)
                mloc[sl] = fminf(mloc[sl], __shfl_xor(mloc[sl], m, 64));
        if (llo == 0) {
#pragma unroll
            for (int mt = 0; mt < 4; ++mt)
#pragma unroll
                for (int q = 0; q < 4; ++q)
                    bminw[w][mt * 16 + lhi * 4 + q] = mloc[mt * 4 + q];
        }
        __syncthreads();
        if (tid < 64) {
            float r = fminf(fminf(bminw[0][tid], bminw[1][tid]),
                            fminf(bminw[2][tid], bminw[3][tid]));
            cutoff_s[tid] = r + MARGIN;   // frozen cutoff for ALL chunks
        }
        __syncthreads();

        // filter chunk 0 (acc still live); cutoff from LDS broadcast
#pragma unroll
        for (int mt = 0; mt < 4; ++mt)
#pragma unroll
            for (int q = 0; q < 4; ++q) {
                const int row = mt * 16 + lhi * 4 + q;
                const float c = cutoff_s[row];
#pragma unroll
                for (int nt = 0; nt < 4; ++nt) {
                    if (acc[mt][nt][q] < c) {
                        const unsigned p = atomicAdd(&hitcnt, 1u);
                        if (p < HCAP)
                            hits[p] = (row << 10) | (w * 64 + nt * 16 + llo);
                        else
                            rowbad[row] = 1;
                    }
                }
            }
    }

    // ======= CHUNKS 1-3: BARRIER-FREE, codegen pinned per iteration =======
#pragma unroll 1
    for (int chunk = 1; chunk < 4; ++chunk) {
        f32x4 acc[4][4];
#pragma unroll
        for (int mt = 0; mt < 4; ++mt)
#pragma unroll
            for (int nt = 0; nt < 4; ++nt) acc[mt][nt] = (f32x4){0.f, 0.f, 0.f, 0.f};

        float e2v[4];
#pragma unroll
        for (int nt = 0; nt < 4; ++nt)
            e2v[nt] = enorm[chunk * 256 + w * 64 + nt * 16 + llo];

        const _Float16* ebase = Efb + (size_t)chunk * 65536 + w * 2048 + lane_off8;
        mfma_chunk(ebase, AhB, llo, lhi, aswz, acc);

#pragma unroll
        for (int mt = 0; mt < 4; ++mt)
#pragma unroll
            for (int q = 0; q < 4; ++q) {
                const int row = mt * 16 + lhi * 4 + q;
                const float c = cutoff_s[row];        // LDS broadcast
#pragma unroll
                for (int nt = 0; nt < 4; ++nt) {
                    const float ds = fmaf(-2.0f, acc[mt][nt][q], e2v[nt]);
                    if (ds < c) {
                        const unsigned p = atomicAdd(&hitcnt, 1u);
                        if (p < HCAP)
                            hits[p] = (row << 10) |
                                      (chunk * 256 + w * 64 + nt * 16 + llo);
                        else
                            rowbad[row] = 1;
                    }
                }
            }
        __builtin_amdgcn_sched_barrier(0);    // MISched fence, no wave sync
    }
    __syncthreads();

    // ============================ EXACT RESCORE ============================
    // One thread per candidate; SEQUENTIAL d=0..255 fma chains (np-identical).
    const int nh = (int)(hitcnt < HCAP ? hitcnt : (unsigned)HCAP);

    for (int hi = tid; hi < nh; hi += 256) {
        const int pk = hits[hi];
        const int rl = pk >> 10, code = pk & 1023;
        const float* xr = X  + (size_t)(rowbase + rl) * DIM;
        const float* er = Et + (size_t)code * DIM;
        float p = 0.f, x2 = 0.f;
#pragma unroll
        for (int j = 0; j < 64; ++j) {          // ascending d, fixed order
            float4 xv = *reinterpret_cast<const float4*>(xr + j * 4);
            float4 ev = *reinterpret_cast<const float4*>(er + j * 4);
            x2 = fmaf(xv.x, xv.x, x2); x2 = fmaf(xv.y, xv.y, x2);
            x2 = fmaf(xv.z, xv.z, x2); x2 = fmaf(xv.w, xv.w, x2);
            p  = fmaf(xv.x, ev.x, p);  p  = fmaf(xv.y, ev.y, p);
            p  = fmaf(xv.z, ev.z, p);  p  = fmaf(xv.w, ev.w, p);
        }
        const float dd = (x2 - 2.0f * p) + enorm[code];
        atomicMin(&minpk[rl], ((u64)fkey(dd) << 10) | (unsigned)code);
    }
    __syncthreads();

    // ------ per-row fallback for rows whose candidates overflowed HCAP ------
    // (statistically near-never; bitwise-identical sequential chains).
    for (int r = 0; r < 64; ++r) {
        if (!rowbad[r]) continue;             // uniform branch (LDS value)
        xs[tid] = X[(size_t)(rowbase + r) * DIM + tid];
        __syncthreads();
        {
            float x2 = 0.f;
            for (int d = 0; d < DIM; ++d) x2 = fmaf(xs[d], xs[d], x2);
            float a0 = 0.f, a1 = 0.f, a2 = 0.f, a3 = 0.f;
            const float* e0 = Et + (size_t)(tid      ) * DIM;
            const float* e1 = Et + (size_t)(tid + 256) * DIM;
            const float* e2p = Et + (size_t)(tid + 512) * DIM;
            const float* e3 = Et + (size_t)(tid + 768) * DIM;
            for (int d = 0; d < DIM; ++d) {
                const float xv = xs[d];
                a0 = fmaf(xv, e0[d], a0);
                a1 = fmaf(xv, e1[d], a1);
                a2 = fmaf(xv, e2p[d], a2);
                a3 = fmaf(xv, e3[d], a3);
            }
            const float d0 = (x2 - 2.0f * a0) + enorm[tid];
            const float d1 = (x2 - 2.0f * a1) + enorm[tid + 256];
            const float d2 = (x2 - 2.0f * a2) + enorm[tid + 512];
            const float d3 = (x2 - 2.0f * a3) + enorm[tid + 768];
            atomicMin(&minpk[r], ((u64)fkey(d0) << 10) | (unsigned)tid);
            atomicMin(&minpk[r], ((u64)fkey(d1) << 10) | (unsigned)(tid + 256));
            atomicMin(&minpk[r], ((u64)fkey(d2) << 10) | (unsigned)(tid + 512));
            atomicMin(&minpk[r], ((u64)fkey(d3) << 10) | (unsigned)(tid + 768));
        }
        __syncthreads();
    }

    // ======================= FUSED EPILOGUE (L2-hot) =======================
    float lsum = 0.f;
    {
        const int row  = tid >> 2;       // 64 rows, 4 threads/row
        const int part = tid & 3;
        const int cw   = (int)(minpk[row] & 1023ULL);
        const float* xrow = X  + (size_t)(rowbase + row) * DIM;
        const float* ew   = Et + (size_t)cw * DIM;
        float* oq = outq + (size_t)(rowbase + row) * DIM;
        if (part == 0) outidx[rowbase + row] = (float)cw;

#pragma unroll
        for (int j = 0; j < 16; ++j) {
            const int d0 = j * 16 + part * 4;
            float4 q = *reinterpret_cast<const float4*>(ew + d0);
            float4 x = *reinterpret_cast<const float4*>(xrow + d0);
            float4 o;
            o.x = x.x + (q.x - x.x);
            o.y = x.y + (q.y - x.y);
            o.z = x.z + (q.z - x.z);
            o.w = x.w + (q.w - x.w);
            *reinterpret_cast<float4*>(oq + d0) = o;
            float dx;
            dx = q.x - x.x; lsum = fmaf(dx, dx, lsum);
            dx = q.y - x.y; lsum = fmaf(dx, dx, lsum);
            dx = q.z - x.z; lsum = fmaf(dx, dx, lsum);
            dx = q.w - x.w; lsum = fmaf(dx, dx, lsum);
        }
    }
    // in-wave reduce, then 4 wave-partials -> one block partial
#pragma unroll
    for (int m = 1; m < 64; m <<= 1) lsum += __shfl_xor(lsum, m, 64);
    if (lane == 0) wlsum[w] = lsum;
    __syncthreads();
    if (tid == 0) {
        float s = wlsum[0] + wlsum[1] + wlsum[2] + wlsum[3];
        partials[blockIdx.x] = s;
    }
}

// ---------------------------------------------------------------------------
__global__ void loss_final(const float* __restrict__ partials, float* __restrict__ out) {
    __shared__ double sd[256];
    const int tid = threadIdx.x;
    double s = 0.0;
    for (int i = tid; i < 1024; i += 256) s += (double)partials[i];
    sd[tid] = s;
    __syncthreads();
    for (int k = 128; k > 0; k >>= 1) {
        if (tid < k) sd[tid] += sd[tid + k];
        __syncthreads();
    }
    if (tid == 0) out[0] = (float)(VQ_BETA * sd[0] / (double)((size_t)N_ROWS * DIM));
}

// ---------------------------------------------------------------------------
extern "C" void kernel_launch(void* const* d_in, const int* in_sizes, int n_in,
                              void* d_out, int out_size, void* d_ws, size_t ws_size,
                              hipStream_t stream) {
    const float* X = (const float*)d_in[0];   // [65536][256]
    const float* E = (const float*)d_in[1];   // [256][1024]

    float* outq    = (float*)d_out;                       // [16777216]
    float* outloss = outq + (size_t)N_ROWS * DIM;         // [1]
    float* outidx  = outloss + 1;                         // [65536] (float-coded)

    float*    Et       = (float*)d_ws;                    // 1 MB
    _Float16* Efb      = (_Float16*)(Et + 262144);        // 512 KB
    float*    enormw   = (float*)(Efb + 262144);          // 4 KB
    float*    partials = enormw + KCODES;                 // 4 KB (1024)

    transpose_e <<<dim3(32, 8), 256, 0, stream>>>(E, Et);
    enorm_kernel<<<4,           256, 0, stream>>>(E, enormw);
    efrag_kernel<<<128,         256, 0, stream>>>(Et, Efb);
    vq_mfma     <<<N_ROWS / 64, 256, 0, stream>>>(X, Efb, enormw, Et,
                                                  outidx, outq, partials);
    loss_final  <<<1,           256, 0, stream>>>(partials, outloss);
}

// Round 19
// 180.393 us; speedup vs baseline: 1.0864x; 1.0864x over previous
//
#include <hip/hip_runtime.h>
#include <float.h>

typedef _Float16 half8 __attribute__((ext_vector_type(8)));
typedef float    f32x4 __attribute__((ext_vector_type(4)));
typedef unsigned long long u64;

#define N_ROWS   65536
#define DIM      256
#define KCODES   1024
#define VQ_BETA  0.25
#define MARGIN   1.5f   // hard bound: need > 2*eps = 0.82 (eps <= 2^-10*||x||*||e|| = 0.41)
#define HCAP     640

// ---------------------------------------------------------------------------
// Order-preserving float->uint key (monotone, handles negatives)
__device__ __forceinline__ unsigned fkey(float f) {
    const unsigned u = __float_as_uint(f);
    return u ^ (0x80000000u | (unsigned)((int)u >> 31));
}

// ---------------------------------------------------------------------------
// Kernel 0: transpose E [256][1024] -> Et [1024][256] fp32 (rescore + gather)
__global__ void transpose_e(const float* __restrict__ E, float* __restrict__ Et) {
    __shared__ float t[32][33];
    const int kt = blockIdx.x * 32;
    const int dt = blockIdx.y * 32;
    const int lx = threadIdx.x & 31;
    const int ly = threadIdx.x >> 5;
#pragma unroll
    for (int i = 0; i < 4; ++i) {
        int d = dt + ly + i * 8;
        t[ly + i * 8][lx] = E[(size_t)d * KCODES + kt + lx];
    }
    __syncthreads();
#pragma unroll
    for (int i = 0; i < 4; ++i) {
        int k = kt + ly + i * 8;
        Et[(size_t)k * DIM + dt + lx] = t[lx][ly + i * 8];
    }
}

// ---------------------------------------------------------------------------
// Kernel 1: e_norm[k] = sum_d E[d][k]^2 (fp32, sequential d order)
__global__ void enorm_kernel(const float* __restrict__ E, float* __restrict__ enorm) {
    const int k = blockIdx.x * 256 + threadIdx.x;
    float s = 0.f;
#pragma unroll 4
    for (int d = 0; d < DIM; ++d) {
        float v = E[(size_t)d * KCODES + k];
        s = fmaf(v, v, s);
    }
    enorm[k] = s;
}

// ---------------------------------------------------------------------------
// Kernel 2: pack Et into fp16 B fragments, wave-coalesced layout.
__global__ void efrag_kernel(const float* __restrict__ Et, _Float16* __restrict__ Efb) {
    const int fid = blockIdx.x * 256 + threadIdx.x;   // 0..32767
    const int lhi   = fid & 3;
    const int llo   = (fid >> 2) & 15;
    const int nt    = (fid >> 6) & 3;
    const int w     = (fid >> 8) & 3;
    const int slice = fid >> 10;                      // 0..31
    const int chunk = slice >> 3, ks = slice & 7;
    const int code  = chunk * 256 + w * 64 + nt * 16 + llo;
    const float* src = Et + (size_t)code * DIM + ks * 32 + lhi * 8;
    half8 h;
#pragma unroll
    for (int j = 0; j < 8; ++j) h[j] = (_Float16)src[j];
    *reinterpret_cast<half8*>(Efb + (size_t)fid * 8) = h;
}

// ---------------------------------------------------------------------------
__device__ __forceinline__ void load_bf2(const _Float16* __restrict__ eb,
                                         half8 (&bf)[2]) {
    bf[0] = *reinterpret_cast<const half8*>(eb);
    bf[1] = *reinterpret_cast<const half8*>(eb + 512);
}
__device__ __forceinline__ void load_af(const char* AhB, int ks, int llo, int lhi,
                                        int aswz, half8 (&af)[4]) {
#pragma unroll
    for (int mt = 0; mt < 4; ++mt) {
        const int addr = ((mt * 16 + llo) * 512 + (ks * 4 + lhi) * 16) ^ aswz;
        af[mt] = *reinterpret_cast<const half8*>(AhB + addr);
    }
}
// One 64-row x 32-code x K=256 accumulation per wave; B direct from global
// (L2-hot) with 4-deep prefetch rotation; A from swizzled LDS; NO barriers.
__device__ __forceinline__ void mfma_chunk(
        const _Float16* __restrict__ ebase, const char* AhB,
        int llo, int lhi, int aswz, f32x4 (&acc)[4][2]) {
    half8 bf[4][2], af[4];
#pragma unroll
    for (int k = 0; k < 4; ++k) load_bf2(ebase + (size_t)k * 8192, bf[k]);
#pragma unroll
    for (int ks = 0; ks < 8; ++ks) {
        const int b = ks & 3;
        const half8 b0 = bf[b][0], b1 = bf[b][1];
        if (ks < 4) load_bf2(ebase + (size_t)(ks + 4) * 8192, bf[b]);
        load_af(AhB, ks, llo, lhi, aswz, af);
#pragma unroll
        for (int mt = 0; mt < 4; ++mt) {
            acc[mt][0] = __builtin_amdgcn_mfma_f32_16x16x32_f16(af[mt], b0, acc[mt][0], 0, 0, 0);
            acc[mt][1] = __builtin_amdgcn_mfma_f32_16x16x32_f16(af[mt], b1, acc[mt][1], 0, 0, 0);
        }
    }
}

// ---------------------------------------------------------------------------
// Kernel 3: round-13 structure (the 141us best) MINUS the memory epilogue.
// Per-chunk running cutoff (2 barriers/chunk), minpk rescore, fallback.
// Epilogue now: loss partial from fp16 X already in LDS (Ah) + L2-hot Et
// gather (error ~1e-4 << 20.48 threshold), write widx + outidx. NO outq
// write, NO X re-read -- ledger algebra (r8 vs r13) showed the K-pass is
// only ~26us and the memory epilogue dominated the remaining ~115us.
__global__ __launch_bounds__(512, 4) void vq_mfma(
        const float* __restrict__ X, const _Float16* __restrict__ Efb,
        const float* __restrict__ enorm, const float* __restrict__ Et,
        float* __restrict__ outidx, int* __restrict__ widx,
        float* __restrict__ partials)
{
    __shared__ _Float16 Ah[64 * 256];     // 32 KB, swizzled
    __shared__ float    bminw[8][64];     // 2 KB
    __shared__ float    cutoff_s[64];
    __shared__ float    rmin_s[64];
    __shared__ u64      minpk[64];        // packed (fkey(dd)<<10)|code
    __shared__ int      rowbad[64];
    __shared__ int      hits[HCAP];       // 2.5 KB
    __shared__ float    xs[DIM];          // 1 KB (fallback row cache)
    __shared__ float    wlsum[8];
    __shared__ unsigned hitcnt;

    const int tid = threadIdx.x;
    const int rowbase = blockIdx.x * 64;

    if (tid == 0) hitcnt = 0;
    if (tid < 64) {
        minpk[tid] = 0xFFFFFFFFFFFFFFFFULL;
        rmin_s[tid] = FLT_MAX;
        rowbad[tid] = 0;
    }

    // ---- stage A tile: fp32 -> fp16 swizzled LDS (8 threads/row) ----
    {
        const int row = tid >> 3;
#pragma unroll
        for (int i = 0; i < 4; ++i) {
            const int g = (tid & 7) + 8 * i;        // 16B-chunk index 0..31
            const float* src = X + (size_t)(rowbase + row) * DIM + g * 8;
            float4 a = *reinterpret_cast<const float4*>(src);
            float4 b = *reinterpret_cast<const float4*>(src + 4);
            half8 h;
            h[0] = (_Float16)a.x; h[1] = (_Float16)a.y;
            h[2] = (_Float16)a.z; h[3] = (_Float16)a.w;
            h[4] = (_Float16)b.x; h[5] = (_Float16)b.y;
            h[6] = (_Float16)b.z; h[7] = (_Float16)b.w;
            const int addr = (row * 512 + g * 16) ^ ((row & 7) << 4);
            *reinterpret_cast<half8*>(reinterpret_cast<char*>(Ah) + addr) = h;
        }
    }
    __syncthreads();

    const int w    = tid >> 6;            // 0..7
    const int lane = tid & 63;
    const int lhi  = lane >> 4, llo = lane & 15;
    const int aswz = (llo & 7) << 4;
    const int lane_off8 = (llo * 4 + lhi) * 8;
    const char* AhB = reinterpret_cast<const char*>(Ah);

    // ======================= SINGLE PASS over 4 chunks =======================
    for (int chunk = 0; chunk < 4; ++chunk) {
        f32x4 acc[4][2];
#pragma unroll
        for (int mt = 0; mt < 4; ++mt)
#pragma unroll
            for (int nt = 0; nt < 2; ++nt) acc[mt][nt] = (f32x4){0.f, 0.f, 0.f, 0.f};

        const _Float16* ebase = Efb + (size_t)chunk * 65536 + w * 1024 + lane_off8;
        mfma_chunk(ebase, AhB, llo, lhi, aswz, acc);

        float e2v[2];
#pragma unroll
        for (int nt = 0; nt < 2; ++nt)
            e2v[nt] = enorm[chunk * 256 + w * 32 + nt * 16 + llo];

        float mloc[16];
#pragma unroll
        for (int mt = 0; mt < 4; ++mt)
#pragma unroll
            for (int q = 0; q < 4; ++q) {
                float m = FLT_MAX;
#pragma unroll
                for (int nt = 0; nt < 2; ++nt) {
                    const float ds = fmaf(-2.0f, acc[mt][nt][q], e2v[nt]);
                    acc[mt][nt][q] = ds;
                    m = fminf(m, ds);
                }
                mloc[mt * 4 + q] = m;
            }
#pragma unroll
        for (int m = 1; m < 16; m <<= 1)
#pragma unroll
            for (int sl = 0; sl < 16; ++sl)
                mloc[sl] = fminf(mloc[sl], __shfl_xor(mloc[sl], m, 64));
        if (llo == 0) {
#pragma unroll
            for (int mt = 0; mt < 4; ++mt)
#pragma unroll
                for (int q = 0; q < 4; ++q)
                    bminw[w][mt * 16 + lhi * 4 + q] = mloc[mt * 4 + q];
        }
        __syncthreads();
        if (tid < 64) {
            float r = bminw[0][tid];
#pragma unroll
            for (int ww = 1; ww < 8; ++ww) r = fminf(r, bminw[ww][tid]);
            r = fminf(rmin_s[tid], r);
            rmin_s[tid]   = r;
            cutoff_s[tid] = r + MARGIN;
        }
        __syncthreads();

#pragma unroll
        for (int mt = 0; mt < 4; ++mt)
#pragma unroll
            for (int q = 0; q < 4; ++q) {
                const int row = mt * 16 + lhi * 4 + q;
                const float cut = cutoff_s[row];
#pragma unroll
                for (int nt = 0; nt < 2; ++nt) {
                    if (acc[mt][nt][q] < cut) {
                        const unsigned p = atomicAdd(&hitcnt, 1u);
                        if (p < HCAP)
                            hits[p] = (row << 10) |
                                      (chunk * 256 + w * 32 + nt * 16 + llo);
                        else
                            rowbad[row] = 1;
                    }
                }
            }
    }
    __syncthreads();

    // ============================ EXACT RESCORE ============================
    // One thread per candidate; SEQUENTIAL d=0..255 fma chains (np-identical).
    const int nh = (int)(hitcnt < HCAP ? hitcnt : (unsigned)HCAP);

    for (int hi = tid; hi < nh; hi += 512) {
        const int pk = hits[hi];
        const int rl = pk >> 10, code = pk & 1023;
        const float* xr = X  + (size_t)(rowbase + rl) * DIM;
        const float* er = Et + (size_t)code * DIM;
        float p = 0.f, x2 = 0.f;
#pragma unroll
        for (int j = 0; j < 64; ++j) {          // ascending d, fixed order
            float4 xv = *reinterpret_cast<const float4*>(xr + j * 4);
            float4 ev = *reinterpret_cast<const float4*>(er + j * 4);
            x2 = fmaf(xv.x, xv.x, x2); x2 = fmaf(xv.y, xv.y, x2);
            x2 = fmaf(xv.z, xv.z, x2); x2 = fmaf(xv.w, xv.w, x2);
            p  = fmaf(xv.x, ev.x, p);  p  = fmaf(xv.y, ev.y, p);
            p  = fmaf(xv.z, ev.z, p);  p  = fmaf(xv.w, ev.w, p);
        }
        const float dd = (x2 - 2.0f * p) + enorm[code];
        atomicMin(&minpk[rl], ((u64)fkey(dd) << 10) | (unsigned)code);
    }
    __syncthreads();

    // ------ per-row fallback for rows whose candidates overflowed HCAP ------
    for (int r = 0; r < 64; ++r) {
        if (!rowbad[r]) continue;             // uniform branch (LDS value)
        if (tid < 256) xs[tid] = X[(size_t)(rowbase + r) * DIM + tid];
        __syncthreads();
        if (tid < 256) {
            float x2 = 0.f;
            for (int d = 0; d < DIM; ++d) x2 = fmaf(xs[d], xs[d], x2);
            float a0 = 0.f, a1 = 0.f, a2 = 0.f, a3 = 0.f;
            const float* e0 = Et + (size_t)(tid      ) * DIM;
            const float* e1 = Et + (size_t)(tid + 256) * DIM;
            const float* e2p = Et + (size_t)(tid + 512) * DIM;
            const float* e3 = Et + (size_t)(tid + 768) * DIM;
            for (int d = 0; d < DIM; ++d) {
                const float xv = xs[d];
                a0 = fmaf(xv, e0[d], a0);
                a1 = fmaf(xv, e1[d], a1);
                a2 = fmaf(xv, e2p[d], a2);
                a3 = fmaf(xv, e3[d], a3);
            }
            const float d0 = (x2 - 2.0f * a0) + enorm[tid];
            const float d1 = (x2 - 2.0f * a1) + enorm[tid + 256];
            const float d2 = (x2 - 2.0f * a2) + enorm[tid + 512];
            const float d3 = (x2 - 2.0f * a3) + enorm[tid + 768];
            atomicMin(&minpk[r], ((u64)fkey(d0) << 10) | (unsigned)tid);
            atomicMin(&minpk[r], ((u64)fkey(d1) << 10) | (unsigned)(tid + 256));
            atomicMin(&minpk[r], ((u64)fkey(d2) << 10) | (unsigned)(tid + 512));
            atomicMin(&minpk[r], ((u64)fkey(d3) << 10) | (unsigned)(tid + 768));
        }
        __syncthreads();
    }

    // ====== LIGHT EPILOGUE: loss from fp16 X in LDS + L2-hot Et gather ======
    float lsum = 0.f;
    {
        const int row  = tid >> 3;       // 64 rows, 8 threads/row
        const int part = tid & 7;
        const int cw   = (int)(minpk[row] & 1023ULL);
        const float* ew = Et + (size_t)cw * DIM;
        if (part == 0) outidx[rowbase + row] = (float)cw;
        if (part == 1) widx[rowbase + row] = cw;

#pragma unroll
        for (int i = 0; i < 4; ++i) {
            const int g = part + 8 * i;          // 16B chunk 0..31
            const int addr = (row * 512 + g * 16) ^ ((row & 7) << 4);
            half8 h = *reinterpret_cast<const half8*>(AhB + addr);
            const int d0 = g * 8;
            float4 qa = *reinterpret_cast<const float4*>(ew + d0);
            float4 qb = *reinterpret_cast<const float4*>(ew + d0 + 4);
            float dx;
            dx = qa.x - (float)h[0]; lsum = fmaf(dx, dx, lsum);
            dx = qa.y - (float)h[1]; lsum = fmaf(dx, dx, lsum);
            dx = qa.z - (float)h[2]; lsum = fmaf(dx, dx, lsum);
            dx = qa.w - (float)h[3]; lsum = fmaf(dx, dx, lsum);
            dx = qb.x - (float)h[4]; lsum = fmaf(dx, dx, lsum);
            dx = qb.y - (float)h[5]; lsum = fmaf(dx, dx, lsum);
            dx = qb.z - (float)h[6]; lsum = fmaf(dx, dx, lsum);
            dx = qb.w - (float)h[7]; lsum = fmaf(dx, dx, lsum);
        }
    }
#pragma unroll
    for (int m = 1; m < 64; m <<= 1) lsum += __shfl_xor(lsum, m, 64);
    if (lane == 0) wlsum[w] = lsum;
    __syncthreads();
    if (tid == 0) {
        float s = wlsum[0];
#pragma unroll
        for (int ww = 1; ww < 8; ++ww) s += wlsum[ww];
        partials[blockIdx.x] = s;
    }
}

// ---------------------------------------------------------------------------
// Kernel 4: pure streaming gather: outq[row] = Et[widx[row]] (== x + (q-x)
// to ~1 ulp). Per wave & iteration: one Et row read (64x16B coalesced,
// L2-hot) -> one 1KB coalesced HBM write. High occupancy, tiny LDS.
__global__ __launch_bounds__(256) void quantize_ep(
        const float* __restrict__ Et, const int* __restrict__ widx,
        float* __restrict__ outq)
{
    const int rowbase = blockIdx.x * 64;
    const f32x4* Et4 = reinterpret_cast<const f32x4*>(Et);
    f32x4* out4 = reinterpret_cast<f32x4*>(outq) + (size_t)blockIdx.x * 4096;
#pragma unroll
    for (int k = 0; k < 16; ++k) {
        const int fi  = k * 256 + threadIdx.x;   // float4 index in block span
        const int row = fi >> 6;                 // 0..63 (uniform per wave)
        const int cw  = widx[rowbase + row];
        out4[fi] = Et4[(size_t)cw * 64 + (fi & 63)];
    }
}

// ---------------------------------------------------------------------------
__global__ void loss_final(const float* __restrict__ partials, float* __restrict__ out) {
    __shared__ double sd[256];
    const int tid = threadIdx.x;
    double s = 0.0;
    for (int i = tid; i < 1024; i += 256) s += (double)partials[i];
    sd[tid] = s;
    __syncthreads();
    for (int k = 128; k > 0; k >>= 1) {
        if (tid < k) sd[tid] += sd[tid + k];
        __syncthreads();
    }
    if (tid == 0) out[0] = (float)(VQ_BETA * sd[0] / (double)((size_t)N_ROWS * DIM));
}

// ---------------------------------------------------------------------------
extern "C" void kernel_launch(void* const* d_in, const int* in_sizes, int n_in,
                              void* d_out, int out_size, void* d_ws, size_t ws_size,
                              hipStream_t stream) {
    const float* X = (const float*)d_in[0];   // [65536][256]
    const float* E = (const float*)d_in[1];   // [256][1024]

    float* outq    = (float*)d_out;                       // [16777216]
    float* outloss = outq + (size_t)N_ROWS * DIM;         // [1]
    float* outidx  = outloss + 1;                         // [65536] (float-coded)

    float*    Et       = (float*)d_ws;                    // 1 MB
    _Float16* Efb      = (_Float16*)(Et + 262144);        // 512 KB
    float*    enormw   = (float*)(Efb + 262144);          // 4 KB
    float*    partials = enormw + KCODES;                 // 4 KB (1024)
    int*      widx     = (int*)(partials + 1024);         // 256 KB

    transpose_e <<<dim3(32, 8), 256, 0, stream>>>(E, Et);
    enorm_kernel<<<4,           256, 0, stream>>>(E, enormw);
    efrag_kernel<<<128,         256, 0, stream>>>(Et, Efb);
    vq_mfma     <<<N_ROWS / 64, 512, 0, stream>>>(X, Efb, enormw, Et,
                                                  outidx, widx, partials);
    quantize_ep <<<N_ROWS / 64, 256, 0, stream>>>(Et, widx, outq);
    loss_final  <<<1,           256, 0, stream>>>(partials, outloss);
}

// Round 20
// 159.269 us; speedup vs baseline: 1.2305x; 1.1326x over previous
//
#include <hip/hip_runtime.h>
#include <float.h>

typedef _Float16 half8 __attribute__((ext_vector_type(8)));
typedef float    f32x4 __attribute__((ext_vector_type(4)));
typedef unsigned long long u64;

#define N_ROWS   65536
#define DIM      256
#define KCODES   1024
#define VQ_BETA  0.25
#define MARGIN   1.5f   // hard bound: need > 2*eps = 0.82 (eps <= 2^-10*||x||*||e|| = 0.41)
#define HCAP     640

// ---------------------------------------------------------------------------
// Order-preserving float->uint key (monotone, handles negatives)
__device__ __forceinline__ unsigned fkey(float f) {
    const unsigned u = __float_as_uint(f);
    return u ^ (0x80000000u | (unsigned)((int)u >> 31));
}

// ---------------------------------------------------------------------------
// Kernel 0 (FUSED prologue): one launch, three independent block ranges.
//   blocks [0,256):   transpose E -> Et  (Et[k][d] = E[d][k])
//   blocks [256,384): Efb fp16 B-fragments DIRECT from E (64B-coalesced gather)
//   blocks [384,388): enorm[k] = sum_d E[d][k]^2 (sequential d order)
// Replaces 3 kernel launches (~4us each, launch-latency dominated) with 1.
__global__ __launch_bounds__(256) void fused_prep(
        const float* __restrict__ E, float* __restrict__ Et,
        _Float16* __restrict__ Efb, float* __restrict__ enorm)
{
    const int b = blockIdx.x;
    if (b < 256) {
        __shared__ float t[32][33];
        const int kt = (b & 31) * 32;
        const int dt = (b >> 5) * 32;
        const int lx = threadIdx.x & 31;
        const int ly = threadIdx.x >> 5;
#pragma unroll
        for (int i = 0; i < 4; ++i) {
            int d = dt + ly + i * 8;
            t[ly + i * 8][lx] = E[(size_t)d * KCODES + kt + lx];
        }
        __syncthreads();
#pragma unroll
        for (int i = 0; i < 4; ++i) {
            int k = kt + ly + i * 8;
            Et[(size_t)k * DIM + dt + lx] = t[lx][ly + i * 8];
        }
    } else if (b < 384) {
        // Efb[fid][j] = Et[code][ks*32+lhi*8+j] = E[(ks*32+lhi*8+j)*1024+code]
        const int fid = (b - 256) * 256 + threadIdx.x;   // 0..32767
        const int lhi   = fid & 3;
        const int llo   = (fid >> 2) & 15;
        const int nt    = (fid >> 6) & 3;
        const int w     = (fid >> 8) & 3;
        const int slice = fid >> 10;                     // 0..31
        const int chunk = slice >> 3, ks = slice & 7;
        const int code  = chunk * 256 + w * 64 + nt * 16 + llo;
        const int dbase = ks * 32 + lhi * 8;
        half8 h;
#pragma unroll
        for (int j = 0; j < 8; ++j)
            h[j] = (_Float16)E[(size_t)(dbase + j) * KCODES + code];
        *reinterpret_cast<half8*>(Efb + (size_t)fid * 8) = h;
    } else {
        const int k = (b - 384) * 256 + threadIdx.x;
        float s = 0.f;
#pragma unroll 4
        for (int d = 0; d < DIM; ++d) {
            float v = E[(size_t)d * KCODES + k];
            s = fmaf(v, v, s);
        }
        enorm[k] = s;
    }
}

// ---------------------------------------------------------------------------
__device__ __forceinline__ void load_bf2(const _Float16* __restrict__ eb,
                                         half8 (&bf)[2]) {
    bf[0] = *reinterpret_cast<const half8*>(eb);
    bf[1] = *reinterpret_cast<const half8*>(eb + 512);
}
__device__ __forceinline__ void load_af(const char* AhB, int ks, int llo, int lhi,
                                        int aswz, half8 (&af)[4]) {
#pragma unroll
    for (int mt = 0; mt < 4; ++mt) {
        const int addr = ((mt * 16 + llo) * 512 + (ks * 4 + lhi) * 16) ^ aswz;
        af[mt] = *reinterpret_cast<const half8*>(AhB + addr);
    }
}
// One 64-row x 32-code x K=256 accumulation per wave; B direct from global
// (L2-hot) with 4-deep prefetch rotation; A from swizzled LDS; NO barriers.
__device__ __forceinline__ void mfma_chunk(
        const _Float16* __restrict__ ebase, const char* AhB,
        int llo, int lhi, int aswz, f32x4 (&acc)[4][2]) {
    half8 bf[4][2], af[4];
#pragma unroll
    for (int k = 0; k < 4; ++k) load_bf2(ebase + (size_t)k * 8192, bf[k]);
#pragma unroll
    for (int ks = 0; ks < 8; ++ks) {
        const int b = ks & 3;
        const half8 b0 = bf[b][0], b1 = bf[b][1];
        if (ks < 4) load_bf2(ebase + (size_t)(ks + 4) * 8192, bf[b]);
        load_af(AhB, ks, llo, lhi, aswz, af);
#pragma unroll
        for (int mt = 0; mt < 4; ++mt) {
            acc[mt][0] = __builtin_amdgcn_mfma_f32_16x16x32_f16(af[mt], b0, acc[mt][0], 0, 0, 0);
            acc[mt][1] = __builtin_amdgcn_mfma_f32_16x16x32_f16(af[mt], b1, acc[mt][1], 0, 0, 0);
        }
    }
}

// ---------------------------------------------------------------------------
// Kernel 1: SINGLE-pass pruned argmin (running cutoff) + fused epilogue.
// Round-13 configuration -- the session's best (total 163.5us): 512 thr =
// 8 waves, 64 rows/block; per-chunk running cutoff (2 barriers/chunk);
// packed 64-bit LDS atomicMin rescore (np first-min tie-break); fused
// L2-hot gather + STE write + loss partial.
// Ten structural variants (occupancy x2, prefetch depth, A-pipelining,
// barrier removal x3, LDS trim, r8 geometry, epilogue shedding) all pinned
// this kernel at 141-150us -- treat as this decomposition's floor.
__global__ __launch_bounds__(512, 4) void vq_mfma(
        const float* __restrict__ X, const _Float16* __restrict__ Efb,
        const float* __restrict__ enorm, const float* __restrict__ Et,
        float* __restrict__ outidx, float* __restrict__ outq,
        float* __restrict__ partials)
{
    __shared__ _Float16 Ah[64 * 256];     // 32 KB, swizzled
    __shared__ float    bminw[8][64];     // 2 KB
    __shared__ float    cutoff_s[64];
    __shared__ float    rmin_s[64];
    __shared__ u64      minpk[64];        // packed (fkey(dd)<<10)|code
    __shared__ int      rowbad[64];
    __shared__ int      hits[HCAP];       // 2.5 KB
    __shared__ float    xs[DIM];          // 1 KB (fallback row cache)
    __shared__ float    wlsum[8];
    __shared__ unsigned hitcnt;

    const int tid = threadIdx.x;
    const int rowbase = blockIdx.x * 64;

    if (tid == 0) hitcnt = 0;
    if (tid < 64) {
        minpk[tid] = 0xFFFFFFFFFFFFFFFFULL;
        rmin_s[tid] = FLT_MAX;
        rowbad[tid] = 0;
    }

    // ---- stage A tile: fp32 -> fp16 swizzled LDS (8 threads/row) ----
    {
        const int row = tid >> 3;
#pragma unroll
        for (int i = 0; i < 4; ++i) {
            const int g = (tid & 7) + 8 * i;        // 16B-chunk index 0..31
            const float* src = X + (size_t)(rowbase + row) * DIM + g * 8;
            float4 a = *reinterpret_cast<const float4*>(src);
            float4 b = *reinterpret_cast<const float4*>(src + 4);
            half8 h;
            h[0] = (_Float16)a.x; h[1] = (_Float16)a.y;
            h[2] = (_Float16)a.z; h[3] = (_Float16)a.w;
            h[4] = (_Float16)b.x; h[5] = (_Float16)b.y;
            h[6] = (_Float16)b.z; h[7] = (_Float16)b.w;
            const int addr = (row * 512 + g * 16) ^ ((row & 7) << 4);
            *reinterpret_cast<half8*>(reinterpret_cast<char*>(Ah) + addr) = h;
        }
    }
    __syncthreads();

    const int w    = tid >> 6;            // 0..7
    const int lane = tid & 63;
    const int lhi  = lane >> 4, llo = lane & 15;
    const int aswz = (llo & 7) << 4;
    const int lane_off8 = (llo * 4 + lhi) * 8;
    const char* AhB = reinterpret_cast<const char*>(Ah);

    // ======================= SINGLE PASS over 4 chunks =======================
    for (int chunk = 0; chunk < 4; ++chunk) {
        f32x4 acc[4][2];
#pragma unroll
        for (int mt = 0; mt < 4; ++mt)
#pragma unroll
            for (int nt = 0; nt < 2; ++nt) acc[mt][nt] = (f32x4){0.f, 0.f, 0.f, 0.f};

        const _Float16* ebase = Efb + (size_t)chunk * 65536 + w * 1024 + lane_off8;
        mfma_chunk(ebase, AhB, llo, lhi, aswz, acc);

        // ds in place (acc := e2 - 2*S~), per-slot min over nt
        float e2v[2];
#pragma unroll
        for (int nt = 0; nt < 2; ++nt)
            e2v[nt] = enorm[chunk * 256 + w * 32 + nt * 16 + llo];

        float mloc[16];
#pragma unroll
        for (int mt = 0; mt < 4; ++mt)
#pragma unroll
            for (int q = 0; q < 4; ++q) {
                float m = FLT_MAX;
#pragma unroll
                for (int nt = 0; nt < 2; ++nt) {
                    const float ds = fmaf(-2.0f, acc[mt][nt][q], e2v[nt]);
                    acc[mt][nt][q] = ds;
                    m = fminf(m, ds);
                }
                mloc[mt * 4 + q] = m;
            }
        // min across the 16 llo lanes (same rows)
#pragma unroll
        for (int m = 1; m < 16; m <<= 1)
#pragma unroll
            for (int sl = 0; sl < 16; ++sl)
                mloc[sl] = fminf(mloc[sl], __shfl_xor(mloc[sl], m, 64));
        if (llo == 0) {
#pragma unroll
            for (int mt = 0; mt < 4; ++mt)
#pragma unroll
                for (int q = 0; q < 4; ++q)
                    bminw[w][mt * 16 + lhi * 4 + q] = mloc[mt * 4 + q];
        }
        __syncthreads();
        if (tid < 64) {
            float r = bminw[0][tid];
#pragma unroll
            for (int ww = 1; ww < 8; ++ww) r = fminf(r, bminw[ww][tid]);
            r = fminf(rmin_s[tid], r);
            rmin_s[tid]   = r;
            cutoff_s[tid] = r + MARGIN;
        }
        __syncthreads();

        // filter this chunk's ds against the running cutoff, append candidates
#pragma unroll
        for (int mt = 0; mt < 4; ++mt)
#pragma unroll
            for (int q = 0; q < 4; ++q) {
                const int row = mt * 16 + lhi * 4 + q;
                const float cut = cutoff_s[row];
#pragma unroll
                for (int nt = 0; nt < 2; ++nt) {
                    if (acc[mt][nt][q] < cut) {
                        const unsigned p = atomicAdd(&hitcnt, 1u);
                        if (p < HCAP)
                            hits[p] = (row << 10) |
                                      (chunk * 256 + w * 32 + nt * 16 + llo);
                        else
                            rowbad[row] = 1;     // row-targeted fallback later
                    }
                }
            }
    }
    __syncthreads();

    // ============================ EXACT RESCORE ============================
    // One thread per candidate; SEQUENTIAL d=0..255 fma chains (np-identical).
    // Winner: one packed 64-bit atomicMin (dd primary, lowest code on ties).
    const int nh = (int)(hitcnt < HCAP ? hitcnt : (unsigned)HCAP);

    for (int hi = tid; hi < nh; hi += 512) {
        const int pk = hits[hi];
        const int rl = pk >> 10, code = pk & 1023;
        const float* xr = X  + (size_t)(rowbase + rl) * DIM;
        const float* er = Et + (size_t)code * DIM;
        float p = 0.f, x2 = 0.f;
#pragma unroll
        for (int j = 0; j < 64; ++j) {          // ascending d, fixed order
            float4 xv = *reinterpret_cast<const float4*>(xr + j * 4);
            float4 ev = *reinterpret_cast<const float4*>(er + j * 4);
            x2 = fmaf(xv.x, xv.x, x2); x2 = fmaf(xv.y, xv.y, x2);
            x2 = fmaf(xv.z, xv.z, x2); x2 = fmaf(xv.w, xv.w, x2);
            p  = fmaf(xv.x, ev.x, p);  p  = fmaf(xv.y, ev.y, p);
            p  = fmaf(xv.z, ev.z, p);  p  = fmaf(xv.w, ev.w, p);
        }
        const float dd = (x2 - 2.0f * p) + enorm[code];
        atomicMin(&minpk[rl], ((u64)fkey(dd) << 10) | (unsigned)code);
    }
    __syncthreads();

    // ------ per-row fallback for rows whose candidates overflowed HCAP ------
    // (statistically near-never; bitwise-identical sequential chains so merged
    //  minima are consistent with the rescore path). Barriers block-uniform.
    for (int r = 0; r < 64; ++r) {
        if (!rowbad[r]) continue;             // uniform branch (LDS value)
        if (tid < 256) xs[tid] = X[(size_t)(rowbase + r) * DIM + tid];
        __syncthreads();
        if (tid < 256) {
            float x2 = 0.f;
            for (int d = 0; d < DIM; ++d) x2 = fmaf(xs[d], xs[d], x2);
            float a0 = 0.f, a1 = 0.f, a2 = 0.f, a3 = 0.f;
            const float* e0 = Et + (size_t)(tid      ) * DIM;
            const float* e1 = Et + (size_t)(tid + 256) * DIM;
            const float* e2p = Et + (size_t)(tid + 512) * DIM;
            const float* e3 = Et + (size_t)(tid + 768) * DIM;
            for (int d = 0; d < DIM; ++d) {
                const float xv = xs[d];
                a0 = fmaf(xv, e0[d], a0);
                a1 = fmaf(xv, e1[d], a1);
                a2 = fmaf(xv, e2p[d], a2);
                a3 = fmaf(xv, e3[d], a3);
            }
            const float d0 = (x2 - 2.0f * a0) + enorm[tid];
            const float d1 = (x2 - 2.0f * a1) + enorm[tid + 256];
            const float d2 = (x2 - 2.0f * a2) + enorm[tid + 512];
            const float d3 = (x2 - 2.0f * a3) + enorm[tid + 768];
            atomicMin(&minpk[r], ((u64)fkey(d0) << 10) | (unsigned)tid);
            atomicMin(&minpk[r], ((u64)fkey(d1) << 10) | (unsigned)(tid + 256));
            atomicMin(&minpk[r], ((u64)fkey(d2) << 10) | (unsigned)(tid + 512));
            atomicMin(&minpk[r], ((u64)fkey(d3) << 10) | (unsigned)(tid + 768));
        }
        __syncthreads();
    }

    // ======================= FUSED EPILOGUE (L2-hot) =======================
    float lsum = 0.f;
    {
        const int row  = tid >> 3;       // 64 rows, 8 threads/row
        const int part = tid & 7;
        const int cw   = (int)(minpk[row] & 1023ULL);
        const float* xrow = X  + (size_t)(rowbase + row) * DIM;
        const float* ew   = Et + (size_t)cw * DIM;
        float* oq = outq + (size_t)(rowbase + row) * DIM;
        if (part == 0) outidx[rowbase + row] = (float)cw;

#pragma unroll
        for (int j = 0; j < 8; ++j) {
            const int d0 = j * 32 + part * 4;
            float4 q = *reinterpret_cast<const float4*>(ew + d0);
            float4 x = *reinterpret_cast<const float4*>(xrow + d0);
            float4 o;
            o.x = x.x + (q.x - x.x);
            o.y = x.y + (q.y - x.y);
            o.z = x.z + (q.z - x.z);
            o.w = x.w + (q.w - x.w);
            *reinterpret_cast<float4*>(oq + d0) = o;
            float dx;
            dx = q.x - x.x; lsum = fmaf(dx, dx, lsum);
            dx = q.y - x.y; lsum = fmaf(dx, dx, lsum);
            dx = q.z - x.z; lsum = fmaf(dx, dx, lsum);
            dx = q.w - x.w; lsum = fmaf(dx, dx, lsum);
        }
    }
    // in-wave reduce, then 8 wave-partials -> one block partial
#pragma unroll
    for (int m = 1; m < 64; m <<= 1) lsum += __shfl_xor(lsum, m, 64);
    if (lane == 0) wlsum[w] = lsum;
    __syncthreads();
    if (tid == 0) {
        float s = wlsum[0];
#pragma unroll
        for (int ww = 1; ww < 8; ++ww) s += wlsum[ww];
        partials[blockIdx.x] = s;
    }
}

// ---------------------------------------------------------------------------
__global__ void loss_final(const float* __restrict__ partials, float* __restrict__ out) {
    __shared__ double sd[256];
    const int tid = threadIdx.x;
    double s = 0.0;
    for (int i = tid; i < 1024; i += 256) s += (double)partials[i];
    sd[tid] = s;
    __syncthreads();
    for (int k = 128; k > 0; k >>= 1) {
        if (tid < k) sd[tid] += sd[tid + k];
        __syncthreads();
    }
    if (tid == 0) out[0] = (float)(VQ_BETA * sd[0] / (double)((size_t)N_ROWS * DIM));
}

// ---------------------------------------------------------------------------
extern "C" void kernel_launch(void* const* d_in, const int* in_sizes, int n_in,
                              void* d_out, int out_size, void* d_ws, size_t ws_size,
                              hipStream_t stream) {
    const float* X = (const float*)d_in[0];   // [65536][256]
    const float* E = (const float*)d_in[1];   // [256][1024]

    float* outq    = (float*)d_out;                       // [16777216]
    float* outloss = outq + (size_t)N_ROWS * DIM;         // [1]
    float* outidx  = outloss + 1;                         // [65536] (float-coded)

    float*    Et       = (float*)d_ws;                    // 1 MB
    _Float16* Efb      = (_Float16*)(Et + 262144);        // 512 KB
    float*    enormw   = (float*)(Efb + 262144);          // 4 KB
    float*    partials = enormw + KCODES;                 // 4 KB (1024)

    fused_prep <<<388,         256, 0, stream>>>(E, Et, Efb, enormw);
    vq_mfma    <<<N_ROWS / 64, 512, 0, stream>>>(X, Efb, enormw, Et,
                                                 outidx, outq, partials);
    loss_final <<<1,           256, 0, stream>>>(partials, outloss);
}